// Round 1
// baseline (459.086 us; speedup 1.0000x reference)
//
#include <hip/hip_runtime.h>
#include <math.h>

#define B_   32
#define C_   1024
#define N_   784
#define NF4  196          // N_/4 float4 per row
#define TD   768
#define AD   256
#define RED_ 64
#define CCH  32           // channel chunks for scores partials
#define OUT0 25690112     // B*C*H*W
#define ROWS (B_*C_)      // 32768

// workspace layout (float offsets)
#define OFF_AVG  0
#define OFF_MAX  32768
#define OFF_CA   65536
#define OFF_G    98304
#define OFF_ATTN 131072
#define OFF_T    156160
#define OFF_S    188928
#define OFF_PART 188960   // B*CCH*N = 802816 -> total 991776 floats (<4MB)

// ---------------- K1: per-row avg & max (1 wave per (b,c) row) ----------------
__global__ void k_avgmax(const float* __restrict__ x, float* __restrict__ avg,
                         float* __restrict__ mx) {
    int row  = blockIdx.x * 4 + (threadIdx.x >> 6);
    int lane = threadIdx.x & 63;
    const float4* xr = (const float4*)(x + (size_t)row * N_);
    float s = 0.f, m = -3.4e38f;
    for (int i = lane; i < NF4; i += 64) {
        float4 v = xr[i];
        s += v.x + v.y + v.z + v.w;
        m = fmaxf(m, fmaxf(fmaxf(v.x, v.y), fmaxf(v.z, v.w)));
    }
    for (int o = 32; o; o >>= 1) {
        s += __shfl_down(s, o, 64);
        m = fmaxf(m, __shfl_down(m, o, 64));
    }
    if (lane == 0) { avg[row] = s * (1.f / (float)N_); mx[row] = m; }
}

// ---------------- K2: per-batch: ch_attn MLP + q + g ----------------
__global__ void k_small(const float* __restrict__ avg, const float* __restrict__ mx,
                        const float* __restrict__ text, const float* __restrict__ w1,
                        const float* __restrict__ w2, const float* __restrict__ wq,
                        const float* __restrict__ wk, float* __restrict__ chattn,
                        float* __restrict__ g) {
    int b = blockIdx.x;
    int t = threadIdx.x;
    __shared__ float h2[128];
    __shared__ float hs[RED_];
    __shared__ float ca[C_];
    __shared__ float q[AD];
    // hidden = relu(z @ w1^T) for z in {avg, mx}
    if (t < 128) {
        const float* z  = (t < 64 ? avg : mx) + (size_t)b * C_;
        const float* wr = w1 + (size_t)(t & 63) * C_;
        float acc = 0.f;
        for (int c = 0; c < C_; ++c) acc += z[c] * wr[c];
        h2[t] = fmaxf(acc, 0.f);
    }
    // q = text @ wq^T  (thread t owns q[t])
    {
        const float* tb = text + (size_t)b * TD;
        const float* wr = wq + (size_t)t * TD;
        float acc = 0.f;
        for (int k = 0; k < TD; ++k) acc += tb[k] * wr[k];
        q[t] = acc;
    }
    __syncthreads();
    if (t < RED_) hs[t] = h2[t] + h2[t + 64];
    __syncthreads();
    // ch_attn = sigmoid(hs @ w2^T)
    for (int j = 0; j < 4; ++j) {
        int c = t + 256 * j;
        const float* wr = w2 + (size_t)c * RED_;
        float acc = 0.f;
        for (int r = 0; r < RED_; ++r) acc += hs[r] * wr[r];
        float cav = 1.f / (1.f + __expf(-acc));
        ca[c] = cav;
        chattn[(size_t)b * C_ + c] = cav;
    }
    // g = (q @ wk) * ch_attn / sqrt(AD)   (ca[c] written by same thread; q synced)
    for (int j = 0; j < 4; ++j) {
        int c = t + 256 * j;
        float acc = 0.f;
        for (int a = 0; a < AD; ++a) acc += q[a] * wk[(size_t)a * C_ + c];
        g[(size_t)b * C_ + c] = acc * ca[c] * 0.0625f;
    }
}

// ---------------- K3: scores partials over channel chunks ----------------
__global__ void k_scores(const float* __restrict__ x, const float* __restrict__ g,
                         float* __restrict__ part) {
    int chunk = blockIdx.x;   // 0..31 (32 channels each)
    int b     = blockIdx.y;
    int t     = threadIdx.x;
    __shared__ float gs[32];
    if (t < 32) gs[t] = g[(size_t)b * C_ + chunk * 32 + t];
    __syncthreads();
    float a0 = 0.f, a1 = 0.f, a2 = 0.f, a3 = 0.f;
    const float* xb = x + ((size_t)b * C_ + (size_t)chunk * 32) * N_;
    for (int c = 0; c < 32; ++c) {
        float gv = gs[c];
        const float* xc = xb + (size_t)c * N_;
        a0 += gv * xc[t];
        a1 += gv * xc[t + 256];
        a2 += gv * xc[t + 512];
        if (t < 16) a3 += gv * xc[t + 768];
    }
    float* p = part + ((size_t)b * CCH + chunk) * N_;
    p[t] = a0; p[t + 256] = a1; p[t + 512] = a2;
    if (t < 16) p[t + 768] = a3;
}

// ---------------- K4: reduce partials + softmax -> attn ----------------
__global__ void k_softmax(const float* __restrict__ part, float* __restrict__ attn) {
    int b = blockIdx.x;
    int t = threadIdx.x;
    int lane = t & 63, wave = t >> 6;
    const float* p = part + (size_t)b * CCH * N_;
    float v0 = 0.f, v1 = 0.f, v2 = 0.f, v3 = 0.f;
    for (int ch = 0; ch < CCH; ++ch) {
        const float* pc = p + (size_t)ch * N_;
        v0 += pc[t]; v1 += pc[t + 256]; v2 += pc[t + 512];
        if (t < 16) v3 += pc[t + 768];
    }
    float m = fmaxf(fmaxf(v0, v1), v2);
    if (t < 16) m = fmaxf(m, v3);
    for (int o = 32; o; o >>= 1) m = fmaxf(m, __shfl_down(m, o, 64));
    __shared__ float rm[4], rs[4];
    if (lane == 0) rm[wave] = m;
    __syncthreads();
    float M = fmaxf(fmaxf(rm[0], rm[1]), fmaxf(rm[2], rm[3]));
    float e0 = __expf(v0 - M), e1 = __expf(v1 - M), e2 = __expf(v2 - M);
    float e3 = (t < 16) ? __expf(v3 - M) : 0.f;
    float ssum = e0 + e1 + e2 + e3;
    for (int o = 32; o; o >>= 1) ssum += __shfl_down(ssum, o, 64);
    if (lane == 0) rs[wave] = ssum;
    __syncthreads();
    float inv = 1.f / (rs[0] + rs[1] + rs[2] + rs[3]);
    float* ab = attn + (size_t)b * N_;
    ab[t] = e0 * inv; ab[t + 256] = e1 * inv; ab[t + 512] = e2 * inv;
    if (t < 16) ab[t + 768] = e3 * inv;
}

// ---------------- K5: t_bc = ch_attn * dot(attn_b, x_row) ----------------
__global__ void k_attend(const float* __restrict__ x, const float* __restrict__ attn,
                         const float* __restrict__ chattn, float* __restrict__ t_out) {
    int row  = blockIdx.x * 4 + (threadIdx.x >> 6);
    int lane = threadIdx.x & 63;
    int b    = row >> 10;
    const float4* xr = (const float4*)(x + (size_t)row * N_);
    const float4* ar = (const float4*)(attn + (size_t)b * N_);
    float s = 0.f;
    for (int i = lane; i < NF4; i += 64) {
        float4 xv = xr[i]; float4 av = ar[i];
        s += xv.x * av.x + xv.y * av.y + xv.z * av.z + xv.w * av.w;
    }
    for (int o = 32; o; o >>= 1) s += __shfl_down(s, o, 64);
    if (lane == 0) t_out[row] = s * chattn[row];
}

// ---------------- K6: s_b = sigmoid( (wo^T wv) . t_b )  (one block) ----------------
__global__ void k_scalar(const float* __restrict__ wv, const float* __restrict__ wo,
                         const float* __restrict__ t_in, float* __restrict__ s_out) {
    __shared__ float wvo[C_];
    int t = threadIdx.x;
    for (int j = 0; j < 4; ++j) {
        int c = t + 256 * j;
        float acc = 0.f;
        for (int a = 0; a < AD; ++a) acc += wo[a] * wv[(size_t)a * C_ + c];
        wvo[c] = acc;
    }
    __syncthreads();
    int wave = t >> 6, lane = t & 63;
    for (int b = wave; b < B_; b += 4) {
        const float* tb = t_in + (size_t)b * C_;
        float acc = 0.f;
        for (int c = lane; c < C_; c += 64) acc += tb[c] * wvo[c];
        for (int o = 32; o; o >>= 1) acc += __shfl_down(acc, o, 64);
        if (lane == 0) s_out[b] = 1.f / (1.f + __expf(-acc));
    }
}

// ---------------- K7: out0 = x*ch_attn*s ; out1 = broadcast s ----------------
__global__ void k_finalize(const float* __restrict__ x, const float* __restrict__ chattn,
                           const float* __restrict__ s, float* __restrict__ out) {
    int blk = blockIdx.x;
    if (blk < ROWS / 4) {
        int row  = blk * 4 + (threadIdx.x >> 6);
        int lane = threadIdx.x & 63;
        float sc = chattn[row] * s[row >> 10];
        const float4* xr = (const float4*)(x + (size_t)row * N_);
        float4* orow = (float4*)(out + (size_t)row * N_);
        for (int i = lane; i < NF4; i += 64) {
            float4 v = xr[i];
            v.x *= sc; v.y *= sc; v.z *= sc; v.w *= sc;
            orow[i] = v;
        }
    } else {
        int idx = (blk - ROWS / 4) * 256 + threadIdx.x;  // float4 index into out1
        if (idx < (B_ * N_) / 4) {
            int b = idx / (N_ / 4);
            float v = s[b];
            ((float4*)(out + OUT0))[idx] = make_float4(v, v, v, v);
        }
    }
}

extern "C" void kernel_launch(void* const* d_in, const int* in_sizes, int n_in,
                              void* d_out, int out_size, void* d_ws, size_t ws_size,
                              hipStream_t stream) {
    const float* x    = (const float*)d_in[0];
    const float* text = (const float*)d_in[1];
    const float* w1   = (const float*)d_in[2];
    const float* w2   = (const float*)d_in[3];
    const float* wq   = (const float*)d_in[4];
    const float* wk   = (const float*)d_in[5];
    const float* wv   = (const float*)d_in[6];
    const float* wo   = (const float*)d_in[7];
    float* out = (float*)d_out;
    float* ws  = (float*)d_ws;

    float* avg  = ws + OFF_AVG;
    float* mx   = ws + OFF_MAX;
    float* ca   = ws + OFF_CA;
    float* g    = ws + OFF_G;
    float* attn = ws + OFF_ATTN;
    float* tt   = ws + OFF_T;
    float* sv   = ws + OFF_S;
    float* part = ws + OFF_PART;

    k_avgmax<<<ROWS / 4, 256, 0, stream>>>(x, avg, mx);
    k_small<<<B_, 256, 0, stream>>>(avg, mx, text, w1, w2, wq, wk, ca, g);
    k_scores<<<dim3(CCH, B_), 256, 0, stream>>>(x, g, part);
    k_softmax<<<B_, 256, 0, stream>>>(part, attn);
    k_attend<<<ROWS / 4, 256, 0, stream>>>(x, attn, ca, tt);
    k_scalar<<<1, 256, 0, stream>>>(wv, wo, tt, sv);
    k_finalize<<<ROWS / 4 + 25, 256, 0, stream>>>(x, ca, sv, out);
}

// Round 2
// 308.151 us; speedup vs baseline: 1.4898x; 1.4898x over previous
//
#include <hip/hip_runtime.h>
#include <math.h>

#define B_   32
#define C_   1024
#define N_   784
#define NF4  196          // N_/4 float4 per row
#define TD   768
#define AD   256
#define RED_ 64
#define OUT0 25690112     // B*C*H*W
#define ROWS (B_*C_)      // 32768
#define SCH  16           // score chunks (64 channels each)

// workspace layout (float offsets)
#define OFF_AVG  0
#define OFF_MAX  32768
#define OFF_CA   65536
#define OFF_Q    98304    // B*AD = 8192
#define OFF_HS   106496   // B*RED = 2048
#define OFF_G    108544   // 32768
#define OFF_WVO  141312   // 1024
#define OFF_ATTN 142336   // B*N = 25088
#define OFF_T    167424   // 32768
#define OFF_S    200192   // 32
#define OFF_PART 200224   // B*SCH*N = 401408  -> end ~601632 floats (~2.3 MB)

// ---------------- K1: per-row avg & max (1 wave per (b,c) row) ----------------
__global__ void k_avgmax(const float* __restrict__ x, float* __restrict__ avg,
                         float* __restrict__ mx) {
    int row  = blockIdx.x * 4 + (threadIdx.x >> 6);
    int lane = threadIdx.x & 63;
    const float4* xr = (const float4*)(x + (size_t)row * N_);
    float s = 0.f, m = -3.4e38f;
    for (int i = lane; i < NF4; i += 64) {
        float4 v = xr[i];
        s += v.x + v.y + v.z + v.w;
        m = fmaxf(m, fmaxf(fmaxf(v.x, v.y), fmaxf(v.z, v.w)));
    }
    for (int o = 32; o; o >>= 1) {
        s += __shfl_down(s, o, 64);
        m = fmaxf(m, __shfl_down(m, o, 64));
    }
    if (lane == 0) { avg[row] = s * (1.f / (float)N_); mx[row] = m; }
}

// ---------------- K2: q[b][a] = dot(text[b], wq[a])  (wave per output) -------
__global__ void k_q(const float* __restrict__ text, const float* __restrict__ wq,
                    float* __restrict__ q) {
    int w    = blockIdx.x * 4 + (threadIdx.x >> 6);   // 0..8191
    int lane = threadIdx.x & 63;
    int b = w >> 8, a = w & 255;
    const float4* tb = (const float4*)(text + (size_t)b * TD);   // 192 float4
    const float4* wr = (const float4*)(wq + (size_t)a * TD);
    float acc = 0.f;
    #pragma unroll
    for (int j = 0; j < 3; ++j) {
        int i = lane + 64 * j;
        float4 tv = tb[i], wv = wr[i];
        acc += tv.x * wv.x + tv.y * wv.y + tv.z * wv.z + tv.w * wv.w;
    }
    for (int o = 32; o; o >>= 1) acc += __shfl_down(acc, o, 64);
    if (lane == 0) q[(size_t)b * AD + a] = acc;
}

// ---------------- K3: wvo[c] = sum_a wo[a]*wv[a][c]  (coalesced c sweep) -----
__global__ void k_wvo(const float* __restrict__ wv, const float* __restrict__ wo,
                      float* __restrict__ wvo) {
    int c = blockIdx.x * 256 + threadIdx.x;
    float acc = 0.f;
    for (int a = 0; a < AD; ++a) acc += wo[a] * wv[(size_t)a * C_ + c];
    wvo[c] = acc;
}

// ---------------- K4: hs[b][r] = relu(avg.w1r) + relu(max.w1r)  (wave/dot) ---
__global__ void k_h(const float* __restrict__ avg, const float* __restrict__ mx,
                    const float* __restrict__ w1, float* __restrict__ hs) {
    int w    = blockIdx.x * 4 + (threadIdx.x >> 6);   // 0..2047
    int lane = threadIdx.x & 63;
    int b = w >> 6, r = w & 63;
    const float4* av = (const float4*)(avg + (size_t)b * C_);    // 256 float4
    const float4* mv = (const float4*)(mx + (size_t)b * C_);
    const float4* wr = (const float4*)(w1 + (size_t)r * C_);
    float aa = 0.f, am = 0.f;
    #pragma unroll
    for (int j = 0; j < 4; ++j) {
        int i = lane + 64 * j;
        float4 wv = wr[i], a4 = av[i], m4 = mv[i];
        aa += wv.x * a4.x + wv.y * a4.y + wv.z * a4.z + wv.w * a4.w;
        am += wv.x * m4.x + wv.y * m4.y + wv.z * m4.z + wv.w * m4.w;
    }
    for (int o = 32; o; o >>= 1) {
        aa += __shfl_down(aa, o, 64);
        am += __shfl_down(am, o, 64);
    }
    if (lane == 0) hs[(size_t)b * RED_ + r] = fmaxf(aa, 0.f) + fmaxf(am, 0.f);
}

// ---------------- K5: ca[b][c] = sigmoid(dot(hs[b], w2[c]))  (wave/dot) ------
__global__ void k_ca(const float* __restrict__ hs, const float* __restrict__ w2,
                     float* __restrict__ ca) {
    int w    = blockIdx.x * 4 + (threadIdx.x >> 6);   // 0..32767
    int lane = threadIdx.x & 63;
    int b = w >> 10, c = w & 1023;
    float p = hs[(size_t)b * RED_ + lane] * w2[(size_t)c * RED_ + lane];
    for (int o = 32; o; o >>= 1) p += __shfl_down(p, o, 64);
    if (lane == 0) ca[(size_t)b * C_ + c] = 1.f / (1.f + __expf(-p));
}

// ---------------- K6: g[b][c] = (sum_a q[b][a]*wk[a][c]) * ca * 1/16 ---------
__global__ void k_g(const float* __restrict__ q, const float* __restrict__ wk,
                    const float* __restrict__ ca, float* __restrict__ g) {
    int b = blockIdx.y;
    int c = blockIdx.x * 256 + threadIdx.x;
    __shared__ float qs[AD];
    if (threadIdx.x < AD) qs[threadIdx.x] = q[(size_t)b * AD + threadIdx.x];
    __syncthreads();
    float acc = 0.f;
    for (int a = 0; a < AD; ++a) acc += qs[a] * wk[(size_t)a * C_ + c];
    g[(size_t)b * C_ + c] = acc * ca[(size_t)b * C_ + c] * 0.0625f;
}

// ---------------- K7: scores partials, 64 channels/block, float4 -------------
__global__ void k_scores(const float* __restrict__ x, const float* __restrict__ g,
                         float* __restrict__ part) {
    int chunk = blockIdx.x;   // 0..15 (64 channels each)
    int b     = blockIdx.y;
    int t     = threadIdx.x;
    int wave  = t >> 6, lane = t & 63;
    __shared__ float gs[64];
    __shared__ float lred[4 * NF4 * 4];   // [wave][196 float4]
    if (t < 64) gs[t] = g[(size_t)b * C_ + chunk * 64 + t];
    __syncthreads();
    const float4* xb4 = (const float4*)(x +
        ((size_t)b * C_ + (size_t)chunk * 64 + (size_t)wave * 16) * N_);
    float4 a0 = {0,0,0,0}, a1 = {0,0,0,0}, a2 = {0,0,0,0}, a3 = {0,0,0,0};
    #pragma unroll
    for (int c = 0; c < 16; ++c) {
        float gv = gs[wave * 16 + c];
        const float4* row = xb4 + (size_t)c * NF4;
        float4 v;
        v = row[lane];       a0.x += gv*v.x; a0.y += gv*v.y; a0.z += gv*v.z; a0.w += gv*v.w;
        v = row[lane + 64];  a1.x += gv*v.x; a1.y += gv*v.y; a1.z += gv*v.z; a1.w += gv*v.w;
        v = row[lane + 128]; a2.x += gv*v.x; a2.y += gv*v.y; a2.z += gv*v.z; a2.w += gv*v.w;
        if (lane < 4) {
            v = row[lane + 192]; a3.x += gv*v.x; a3.y += gv*v.y; a3.z += gv*v.z; a3.w += gv*v.w;
        }
    }
    float4* l4 = (float4*)lred;
    l4[wave * NF4 + lane]       = a0;
    l4[wave * NF4 + lane + 64]  = a1;
    l4[wave * NF4 + lane + 128] = a2;
    if (lane < 4) l4[wave * NF4 + lane + 192] = a3;
    __syncthreads();
    if (t < NF4) {
        float4 s0 = l4[t], s1 = l4[NF4 + t], s2 = l4[2 * NF4 + t], s3 = l4[3 * NF4 + t];
        float4 r;
        r.x = s0.x + s1.x + s2.x + s3.x;
        r.y = s0.y + s1.y + s2.y + s3.y;
        r.z = s0.z + s1.z + s2.z + s3.z;
        r.w = s0.w + s1.w + s2.w + s3.w;
        ((float4*)(part + ((size_t)b * SCH + chunk) * N_))[t] = r;
    }
}

// ---------------- K8: reduce partials + softmax -> attn ----------------------
__global__ void k_softmax(const float* __restrict__ part, float* __restrict__ attn) {
    int b = blockIdx.x;
    int t = threadIdx.x;
    int lane = t & 63, wave = t >> 6;
    const float* p = part + (size_t)b * SCH * N_;
    float v0 = 0.f, v1 = 0.f, v2 = 0.f, v3 = 0.f;
    for (int ch = 0; ch < SCH; ++ch) {
        const float* pc = p + (size_t)ch * N_;
        v0 += pc[t]; v1 += pc[t + 256]; v2 += pc[t + 512];
        if (t < 16) v3 += pc[t + 768];
    }
    float m = fmaxf(fmaxf(v0, v1), v2);
    if (t < 16) m = fmaxf(m, v3);
    for (int o = 32; o; o >>= 1) m = fmaxf(m, __shfl_down(m, o, 64));
    __shared__ float rm[4], rs[4];
    if (lane == 0) rm[wave] = m;
    __syncthreads();
    float M = fmaxf(fmaxf(rm[0], rm[1]), fmaxf(rm[2], rm[3]));
    float e0 = __expf(v0 - M), e1 = __expf(v1 - M), e2 = __expf(v2 - M);
    float e3 = (t < 16) ? __expf(v3 - M) : 0.f;
    float ssum = e0 + e1 + e2 + e3;
    for (int o = 32; o; o >>= 1) ssum += __shfl_down(ssum, o, 64);
    if (lane == 0) rs[wave] = ssum;
    __syncthreads();
    float inv = 1.f / (rs[0] + rs[1] + rs[2] + rs[3]);
    float* ab = attn + (size_t)b * N_;
    ab[t] = e0 * inv; ab[t + 256] = e1 * inv; ab[t + 512] = e2 * inv;
    if (t < 16) ab[t + 768] = e3 * inv;
}

// ---------------- K9: t_bc = ch_attn * dot(attn_b, x_row) --------------------
__global__ void k_attend(const float* __restrict__ x, const float* __restrict__ attn,
                         const float* __restrict__ chattn, float* __restrict__ t_out) {
    int row  = blockIdx.x * 4 + (threadIdx.x >> 6);
    int lane = threadIdx.x & 63;
    int b    = row >> 10;
    const float4* xr = (const float4*)(x + (size_t)row * N_);
    const float4* ar = (const float4*)(attn + (size_t)b * N_);
    float s = 0.f;
    for (int i = lane; i < NF4; i += 64) {
        float4 xv = xr[i]; float4 av = ar[i];
        s += xv.x * av.x + xv.y * av.y + xv.z * av.z + xv.w * av.w;
    }
    for (int o = 32; o; o >>= 1) s += __shfl_down(s, o, 64);
    if (lane == 0) t_out[row] = s * chattn[row];
}

// ---------------- K10: s_b = sigmoid(dot(wvo, t_b))  (wave per b) ------------
__global__ void k_scalar(const float* __restrict__ wvo, const float* __restrict__ t_in,
                         float* __restrict__ s_out) {
    int b    = blockIdx.x * 4 + (threadIdx.x >> 6);   // 0..31
    int lane = threadIdx.x & 63;
    const float4* tb = (const float4*)(t_in + (size_t)b * C_);   // 256 float4
    const float4* wv = (const float4*)wvo;
    float acc = 0.f;
    #pragma unroll
    for (int j = 0; j < 4; ++j) {
        int i = lane + 64 * j;
        float4 tv = tb[i], wvv = wv[i];
        acc += tv.x * wvv.x + tv.y * wvv.y + tv.z * wvv.z + tv.w * wvv.w;
    }
    for (int o = 32; o; o >>= 1) acc += __shfl_down(acc, o, 64);
    if (lane == 0) s_out[b] = 1.f / (1.f + __expf(-acc));
}

// ---------------- K11: out0 = x*ch_attn*s ; out1 = broadcast s ---------------
__global__ void k_finalize(const float* __restrict__ x, const float* __restrict__ chattn,
                           const float* __restrict__ s, float* __restrict__ out) {
    int blk = blockIdx.x;
    if (blk < ROWS / 4) {
        int row  = blk * 4 + (threadIdx.x >> 6);
        int lane = threadIdx.x & 63;
        float sc = chattn[row] * s[row >> 10];
        const float4* xr = (const float4*)(x + (size_t)row * N_);
        float4* orow = (float4*)(out + (size_t)row * N_);
        for (int i = lane; i < NF4; i += 64) {
            float4 v = xr[i];
            v.x *= sc; v.y *= sc; v.z *= sc; v.w *= sc;
            orow[i] = v;
        }
    } else {
        int idx = (blk - ROWS / 4) * 256 + threadIdx.x;  // float4 index into out1
        if (idx < (B_ * N_) / 4) {
            int b = idx / (N_ / 4);
            float v = s[b];
            ((float4*)(out + OUT0))[idx] = make_float4(v, v, v, v);
        }
    }
}

extern "C" void kernel_launch(void* const* d_in, const int* in_sizes, int n_in,
                              void* d_out, int out_size, void* d_ws, size_t ws_size,
                              hipStream_t stream) {
    const float* x    = (const float*)d_in[0];
    const float* text = (const float*)d_in[1];
    const float* w1   = (const float*)d_in[2];
    const float* w2   = (const float*)d_in[3];
    const float* wq   = (const float*)d_in[4];
    const float* wk   = (const float*)d_in[5];
    const float* wv   = (const float*)d_in[6];
    const float* wo   = (const float*)d_in[7];
    float* out = (float*)d_out;
    float* ws  = (float*)d_ws;

    float* avg  = ws + OFF_AVG;
    float* mx   = ws + OFF_MAX;
    float* ca   = ws + OFF_CA;
    float* q    = ws + OFF_Q;
    float* hs   = ws + OFF_HS;
    float* g    = ws + OFF_G;
    float* wvo  = ws + OFF_WVO;
    float* attn = ws + OFF_ATTN;
    float* tt   = ws + OFF_T;
    float* sv   = ws + OFF_S;
    float* part = ws + OFF_PART;

    k_avgmax<<<ROWS / 4, 256, 0, stream>>>(x, avg, mx);
    k_q<<<(B_ * AD) / 4, 256, 0, stream>>>(text, wq, q);
    k_wvo<<<C_ / 256, 256, 0, stream>>>(wv, wo, wvo);
    k_h<<<(B_ * RED_) / 4, 256, 0, stream>>>(avg, mx, w1, hs);
    k_ca<<<(B_ * C_) / 4, 256, 0, stream>>>(hs, w2, ca);
    k_g<<<dim3(C_ / 256, B_), 256, 0, stream>>>(q, wk, ca, g);
    k_scores<<<dim3(SCH, B_), 256, 0, stream>>>(x, g, part);
    k_softmax<<<B_, 256, 0, stream>>>(part, attn);
    k_attend<<<ROWS / 4, 256, 0, stream>>>(x, attn, ca, tt);
    k_scalar<<<B_ / 4, 256, 0, stream>>>(wvo, tt, sv);
    k_finalize<<<ROWS / 4 + 25, 256, 0, stream>>>(x, ca, sv, out);
}